// Round 6
// baseline (866.194 us; speedup 1.0000x reference)
//
#include <hip/hip_runtime.h>
#include <hip/hip_fp16.h>

// B=64, I=2048, D=8, O=32, K=16.  e-layout o-major: e = o*16 + k.
//
// Round-5 postmortem: cooperative grid.sync cost ~150us/sync -> reverted to
// the 6-launch structure. This round doubles pass occupancy instead:
// grid 1024 = (qh = bx>>8: b-QUARTER, 16 b's) x (ch = bx&255: 8-i chunk).
// x_lds halves to 4KB -> LDS 36KB <= 40KB and __launch_bounds__(512,8)
// (VGPR<=64, which round 4 already achieved) -> 4 blocks/CU = 8 waves/SIMD
// (was 2 blocks/CU = 4 waves/SIMD, VALUBusy 36% -> latency-bound).
// part stays [64][256][512] fp16 (16 MB); reduce kernel unchanged.
//
// wave w = i-slot (8 i/chunk); lane: o = l&31, kk = l>>5.
// W[i][o][:][kk*8..+8] = 64 regs, asm-pinned. Softmax o-sum via DPP (VALU)
// + 1 ds_swizzle. red staged fp16 (f32 accumulation), conflict-free.

struct __align__(16) H8 { __half2 a, b, c, d; };
struct __align__(8)  H4 { __half2 a, b; };

template<int CTRL>
__device__ __forceinline__ float dppadd(float v) {   // v + dpp_perm(v), VALU-only
    return v + __int_as_float(__builtin_amdgcn_update_dpp(
        0, __float_as_int(v), CTRL, 0xF, 0xF, true));
}

template<int PASS0>
__global__ __launch_bounds__(512, 8)   // VGPR<=64 -> 4 blocks/CU (LDS 36KB<=40)
void pass_kernel(const float* __restrict__ x,    // [64][2048][8]
                 const float* __restrict__ W,    // [2048][32][8][16]
                 const float* __restrict__ vin,  // [64][512] f32, o-major
                 __half* __restrict__ part)      // [64][256][512] fp16
{
    __shared__ __align__(16) float  x_lds[16 * 64];    //  4 KB: [bl][il*8+d]
    __shared__ __align__(16) __half redh[2][16][512];  // 32 KB: [par][slot*2+bq][e]

    const int t  = threadIdx.x;
    const int w  = t >> 6;
    const int l  = t & 63;
    const int o  = l & 31;
    const int kk = l >> 5;
    const int bx = blockIdx.x;
    const int ch = bx & 255;
    const int qh = bx >> 8;          // b-quarter: b in [qh*16, qh*16+16)
    const int i  = ch * 8 + w;

    // ---- W[i][o][d][kk-half] -> 64 registers, PINNED (stops load sinking) --
    float Wr[8][8];
    {
        const float* wp = W + (size_t)(i * 32 + o) * 128 + kk * 8;
        #pragma unroll
        for (int d = 0; d < 8; ++d) {
            float4 a = *(const float4*)(wp + d * 16);
            float4 b = *(const float4*)(wp + d * 16 + 4);
            Wr[d][0] = a.x; Wr[d][1] = a.y; Wr[d][2] = a.z; Wr[d][3] = a.w;
            Wr[d][4] = b.x; Wr[d][5] = b.y; Wr[d][6] = b.z; Wr[d][7] = b.w;
        }
        #pragma unroll
        for (int d = 0; d < 8; ++d)
            #pragma unroll
            for (int j = 0; j < 8; ++j)
                asm volatile("" : "+v"(Wr[d][j]));
    }
    // ---- stage x[b-quarter, chunk, :]: 1024 floats, float4 on t<256 --------
    if (t < 256) {
        const int f = t * 4, bl = f >> 6, rr = f & 63;
        *(float4*)&x_lds[f] =
            *(const float4*)(x + (size_t)(qh * 16 + bl) * 16384 + ch * 64 + rr);
    }

    #pragma unroll 2
    for (int g = 0; g < 8; ++g) {        // 2 b's per group, 8 groups
        __syncthreads();                 // redh[g&1] free; g=0: x_lds ready

        // ---- fold(g-1): sum 8 i-slots of redh[(g-1)&1], write part (fp16) --
        if (g && t < 256) {
            const int bqf = t >> 7;
            const int hx  = (t & 127) * 4;           // half index in [0,512)
            const __half* rp = &redh[(g - 1) & 1][0][0];
            float a0 = 0.f, a1 = 0.f, a2 = 0.f, a3 = 0.f;
            #pragma unroll
            for (int s = 0; s < 8; ++s) {
                H4 v = *(const H4*)(rp + (s * 2 + bqf) * 512 + hx);
                float2 f0 = __half22float2(v.a), f1 = __half22float2(v.b);
                a0 += f0.x; a1 += f0.y; a2 += f1.x; a3 += f1.y;
            }
            const int b = qh * 16 + (g - 1) * 2 + bqf;
            H4 o4;
            o4.a = __floats2half2_rn(a0, a1);
            o4.b = __floats2half2_rn(a2, a3);
            *(H4*)(part + ((size_t)b * 256 + ch) * 512 + hx) = o4;
        }

        // ---- compute(g) -> redh[g&1] --------------------------------------
        #pragma unroll
        for (int bq = 0; bq < 2; ++bq) {
            const int bl = g * 2 + bq;
            float4 va, vb;
            if (!PASS0) {                // issue v loads first (L1/L2 latency)
                const float* vp = vin + (size_t)(qh * 16 + bl) * 512 + o * 16 + kk * 8;
                va = *(const float4*)vp;
                vb = *(const float4*)(vp + 4);
            }
            float4 xa = *(const float4*)&x_lds[bl * 64 + w * 8];   // broadcast
            float4 xb = *(const float4*)&x_lds[bl * 64 + w * 8 + 4];
            float xr[8] = {xa.x, xa.y, xa.z, xa.w, xb.x, xb.y, xb.z, xb.w};
            float uh[8];
            #pragma unroll
            for (int j = 0; j < 8; ++j) uh[j] = 0.f;
            #pragma unroll
            for (int d = 0; d < 8; ++d) {
                #pragma unroll
                for (int j = 0; j < 8; ++j)
                    uh[j] = fmaf(xr[d], Wr[d][j], uh[j]);
            }
            float c;
            if (PASS0) {
                c = 0.03125f;            // softmax of zeros
            } else {
                float logit = uh[0] * va.x;
                logit = fmaf(uh[1], va.y, logit);
                logit = fmaf(uh[2], va.z, logit);
                logit = fmaf(uh[3], va.w, logit);
                logit = fmaf(uh[4], vb.x, logit);
                logit = fmaf(uh[5], vb.y, logit);
                logit = fmaf(uh[6], vb.z, logit);
                logit = fmaf(uh[7], vb.w, logit);
                logit += __shfl_xor(logit, 32, 64);   // combine k-halves (1 DS)
                float ex = __expf(logit);             // |logit| small: no max
                float sm = ex;                        // o-sum: 4 DPP + xor16
                sm = dppadd<0xB1>(sm);                // quad_perm xor1
                sm = dppadd<0x4E>(sm);                // quad_perm xor2
                sm = dppadd<0x124>(sm);               // row_ror:4
                sm = dppadd<0x128>(sm);               // row_ror:8
                sm += __int_as_float(__builtin_amdgcn_ds_swizzle(
                          __float_as_int(sm), 0x401F));   // xor16 within 32
                c = __fdividef(ex, sm);
            }
            H8 pk;
            pk.a = __floats2half2_rn(c * uh[0], c * uh[1]);
            pk.b = __floats2half2_rn(c * uh[2], c * uh[3]);
            pk.c = __floats2half2_rn(c * uh[4], c * uh[5]);
            pk.d = __floats2half2_rn(c * uh[6], c * uh[7]);
            *(H8*)&redh[g & 1][w * 2 + bq][o * 16 + kk * 8] = pk;   // 1 b128
        }
    }
    __syncthreads();
    if (t < 256) {   // ---- epilogue fold(g=7) from redh[1] ------------------
        const int bqf = t >> 7;
        const int hx  = (t & 127) * 4;
        const __half* rp = &redh[1][0][0];
        float a0 = 0.f, a1 = 0.f, a2 = 0.f, a3 = 0.f;
        #pragma unroll
        for (int s = 0; s < 8; ++s) {
            H4 v = *(const H4*)(rp + (s * 2 + bqf) * 512 + hx);
            float2 f0 = __half22float2(v.a), f1 = __half22float2(v.b);
            a0 += f0.x; a1 += f0.y; a2 += f1.x; a3 += f1.y;
        }
        const int b = qh * 16 + 14 + bqf;
        H4 o4;
        o4.a = __floats2half2_rn(a0, a1);
        o4.b = __floats2half2_rn(a2, a3);
        *(H4*)(part + ((size_t)b * 256 + ch) * 512 + hx) = o4;
    }
}

// ---------------------------------------------------------------------------
// Reduce (unchanged from round 4): grid 512 = (b = bx>>3) x (q = bx&7: 64-e
// slice = 4 complete o's). 1024 threads: f = t&7 (16B = 8 halves), c0 = t>>3
// (chunk row in [0,128)); 2 x 16B loads/thread, f32 accumulate, 3-stage LDS
// fold, squash tail. PHASE 0: vsum=v; 1: vsum+=v; 2: out[b][o][k]=v.
// ---------------------------------------------------------------------------
template<int PHASE>
__global__ __launch_bounds__(1024)
void reduce_kernel(const __half* __restrict__ part,
                   float* __restrict__ vsum,
                   float* __restrict__ out)
{
    __shared__ __align__(16) float sA[128][64];   // 32 KB
    __shared__ __align__(16) float sB[16][64];    //  4 KB
    const int bx = blockIdx.x;
    const int b  = bx >> 3;
    const int q  = bx & 7;
    const int t  = threadIdx.x;
    const int f  = t & 7;
    const int c0 = t >> 3;                        // chunk row in [0,128)

    const __half* p0 = part + ((size_t)b * 256 + c0) * 512 + q * 64 + f * 8;
    float acc[8] = {0.f, 0.f, 0.f, 0.f, 0.f, 0.f, 0.f, 0.f};
    #pragma unroll
    for (int rr = 0; rr < 2; ++rr) {              // rows c0, c0+128
        H8 v = *(const H8*)(p0 + (size_t)rr * 128 * 512);
        float2 f0 = __half22float2(v.a), f1 = __half22float2(v.b),
               f2 = __half22float2(v.c), f3 = __half22float2(v.d);
        acc[0] += f0.x; acc[1] += f0.y; acc[2] += f1.x; acc[3] += f1.y;
        acc[4] += f2.x; acc[5] += f2.y; acc[6] += f3.x; acc[7] += f3.y;
    }
    *(float4*)&sA[c0][f * 8]     = make_float4(acc[0], acc[1], acc[2], acc[3]);
    *(float4*)&sA[c0][f * 8 + 4] = make_float4(acc[4], acc[5], acc[6], acc[7]);
    __syncthreads();

    {                                             // 128 rows -> 16
        const int e = t & 63, r4 = t >> 6;        // r4 in [0,16)
        float sb = 0.f;
        #pragma unroll
        for (int k2 = 0; k2 < 8; ++k2) sb += sA[r4 + k2 * 16][e];
        sB[r4][e] = sb;
    }
    __syncthreads();

    if (t < 64) {                                 // one wave: 16 rows, squash
        float s1 = 0.f;
        #pragma unroll
        for (int r = 0; r < 16; ++r) s1 += sB[r][t];
        float sq = s1 * s1;
        #pragma unroll
        for (int off = 8; off >= 1; off >>= 1)
            sq += __shfl_xor(sq, off, 16);        // sum over 16 k within o
        float v = (sq / (1.f + sq) * rsqrtf(sq + 1e-7f)) * s1;
        const size_t idx = (size_t)b * 512 + q * 64 + t;
        if (PHASE == 2)      out[idx]   = v;      // e = o*16+k == [b][o][k]
        else if (PHASE == 1) vsum[idx] += v;
        else                 vsum[idx]  = v;
    }
}

// ---------------------------------------------------------------------------
extern "C" void kernel_launch(void* const* d_in, const int* in_sizes, int n_in,
                              void* d_out, int out_size, void* d_ws, size_t ws_size,
                              hipStream_t stream)
{
    const float* x = (const float*)d_in[0];
    const float* W = (const float*)d_in[1];
    float* out = (float*)d_out;
    char* ws = (char*)d_ws;

    const size_t partB = (size_t)64 * 256 * 512 * 2;   // 16 MB (fp16)
    const size_t vsumB = (size_t)64 * 512 * 4;         // 128 KB
    if (ws_size < partB + vsumB) return;               // never taken

    __half* part = (__half*)ws;
    float*  vsum = (float*)(ws + partB);

    // round 0: c uniform -> v0; vsum = v0
    pass_kernel<1><<<1024, 512, 0, stream>>>(x, W, vsum, part);
    reduce_kernel<0><<<512, 1024, 0, stream>>>(part, vsum, out);
    // round 1: logits = u_hat . v0 -> v1; vsum = v0 + v1
    pass_kernel<0><<<1024, 512, 0, stream>>>(x, W, vsum, part);
    reduce_kernel<1><<<512, 1024, 0, stream>>>(part, vsum, out);
    // round 2: logits = u_hat . (v0+v1) -> v2 = output
    pass_kernel<0><<<1024, 512, 0, stream>>>(x, W, vsum, part);
    reduce_kernel<2><<<512, 1024, 0, stream>>>(part, vsum, out);
}

// Round 7
// 189.902 us; speedup vs baseline: 4.5613x; 4.5613x over previous
//
#include <hip/hip_runtime.h>
#include <hip/hip_fp16.h>

// B=64, I=2048, D=8, O=32, K=16.  e-layout o-major: e = o*16 + k.
//
// Round-6 postmortem: launch_bounds(512,8) halved the VGPR budget to 32 ->
// Wr[8][8] spilled to scratch (FETCH 23.7MB -> 823MB, pass 42 -> 286us).
// BUT occupancy did reach 75% with grid=1024 + 36KB LDS (4 blocks/CU).
// This round: grid 1024 geometry + launch_bounds(512,4) (round-4-proven
// VGPR=64, no spill). VGPR=64 alone allows 8 waves/SIMD, so the (512,4)
// bound does not cap the 4-blocks/CU occupancy; round 4 was grid-limited.
//
// grid 1024 = (qh = bx>>8: b-quarter, 16 b's) x (ch = bx&255: 8-i chunk).
// wave w = i-slot; lane: o = l&31, kk = l>>5. W[i][o][:][kk*8..+8] = 64 regs,
// asm-pinned. Softmax o-sum via DPP (VALU) + 1 ds_swizzle. red staged fp16
// (f32 accumulation), conflict-free. part [64][256][512] fp16; reduce as r4.

struct __align__(16) H8 { __half2 a, b, c, d; };
struct __align__(8)  H4 { __half2 a, b; };

template<int CTRL>
__device__ __forceinline__ float dppadd(float v) {   // v + dpp_perm(v), VALU-only
    return v + __int_as_float(__builtin_amdgcn_update_dpp(
        0, __float_as_int(v), CTRL, 0xF, 0xF, true));
}

template<int PASS0>
__global__ __launch_bounds__(512, 4)   // 128-VGPR budget: no Wr spill (r4-proven)
void pass_kernel(const float* __restrict__ x,    // [64][2048][8]
                 const float* __restrict__ W,    // [2048][32][8][16]
                 const float* __restrict__ vin,  // [64][512] f32, o-major
                 __half* __restrict__ part)      // [64][256][512] fp16
{
    __shared__ __align__(16) float  x_lds[16 * 64];    //  4 KB: [bl][il*8+d]
    __shared__ __align__(16) __half redh[2][16][512];  // 32 KB: [par][slot*2+bq][e]

    const int t  = threadIdx.x;
    const int w  = t >> 6;
    const int l  = t & 63;
    const int o  = l & 31;
    const int kk = l >> 5;
    const int bx = blockIdx.x;
    const int ch = bx & 255;
    const int qh = bx >> 8;          // b-quarter: b in [qh*16, qh*16+16)
    const int i  = ch * 8 + w;

    // ---- W[i][o][d][kk-half] -> 64 registers, PINNED (stops load sinking) --
    float Wr[8][8];
    {
        const float* wp = W + (size_t)(i * 32 + o) * 128 + kk * 8;
        #pragma unroll
        for (int d = 0; d < 8; ++d) {
            float4 a = *(const float4*)(wp + d * 16);
            float4 b = *(const float4*)(wp + d * 16 + 4);
            Wr[d][0] = a.x; Wr[d][1] = a.y; Wr[d][2] = a.z; Wr[d][3] = a.w;
            Wr[d][4] = b.x; Wr[d][5] = b.y; Wr[d][6] = b.z; Wr[d][7] = b.w;
        }
        #pragma unroll
        for (int d = 0; d < 8; ++d)
            #pragma unroll
            for (int j = 0; j < 8; ++j)
                asm volatile("" : "+v"(Wr[d][j]));
    }
    // ---- stage x[b-quarter, chunk, :]: 1024 floats, float4 on t<256 --------
    if (t < 256) {
        const int f = t * 4, bl = f >> 6, rr = f & 63;
        *(float4*)&x_lds[f] =
            *(const float4*)(x + (size_t)(qh * 16 + bl) * 16384 + ch * 64 + rr);
    }

    #pragma unroll 2
    for (int g = 0; g < 8; ++g) {        // 2 b's per group, 8 groups
        __syncthreads();                 // redh[g&1] free; g=0: x_lds ready

        // ---- fold(g-1): sum 8 i-slots of redh[(g-1)&1], write part (fp16) --
        if (g && t < 256) {
            const int bqf = t >> 7;
            const int hx  = (t & 127) * 4;           // half index in [0,512)
            const __half* rp = &redh[(g - 1) & 1][0][0];
            float a0 = 0.f, a1 = 0.f, a2 = 0.f, a3 = 0.f;
            #pragma unroll
            for (int s = 0; s < 8; ++s) {
                H4 v = *(const H4*)(rp + (s * 2 + bqf) * 512 + hx);
                float2 f0 = __half22float2(v.a), f1 = __half22float2(v.b);
                a0 += f0.x; a1 += f0.y; a2 += f1.x; a3 += f1.y;
            }
            const int b = qh * 16 + (g - 1) * 2 + bqf;
            H4 o4;
            o4.a = __floats2half2_rn(a0, a1);
            o4.b = __floats2half2_rn(a2, a3);
            *(H4*)(part + ((size_t)b * 256 + ch) * 512 + hx) = o4;
        }

        // ---- compute(g) -> redh[g&1] --------------------------------------
        #pragma unroll
        for (int bq = 0; bq < 2; ++bq) {
            const int bl = g * 2 + bq;
            float4 va, vb;
            if (!PASS0) {                // issue v loads first (L1/L2 latency)
                const float* vp = vin + (size_t)(qh * 16 + bl) * 512 + o * 16 + kk * 8;
                va = *(const float4*)vp;
                vb = *(const float4*)(vp + 4);
            }
            float4 xa = *(const float4*)&x_lds[bl * 64 + w * 8];   // broadcast
            float4 xb = *(const float4*)&x_lds[bl * 64 + w * 8 + 4];
            float xr[8] = {xa.x, xa.y, xa.z, xa.w, xb.x, xb.y, xb.z, xb.w};
            float uh[8];
            #pragma unroll
            for (int j = 0; j < 8; ++j) uh[j] = 0.f;
            #pragma unroll
            for (int d = 0; d < 8; ++d) {
                #pragma unroll
                for (int j = 0; j < 8; ++j)
                    uh[j] = fmaf(xr[d], Wr[d][j], uh[j]);
            }
            float c;
            if (PASS0) {
                c = 0.03125f;            // softmax of zeros
            } else {
                float logit = uh[0] * va.x;
                logit = fmaf(uh[1], va.y, logit);
                logit = fmaf(uh[2], va.z, logit);
                logit = fmaf(uh[3], va.w, logit);
                logit = fmaf(uh[4], vb.x, logit);
                logit = fmaf(uh[5], vb.y, logit);
                logit = fmaf(uh[6], vb.z, logit);
                logit = fmaf(uh[7], vb.w, logit);
                logit += __shfl_xor(logit, 32, 64);   // combine k-halves (1 DS)
                float ex = __expf(logit);             // |logit| small: no max
                float sm = ex;                        // o-sum: 4 DPP + xor16
                sm = dppadd<0xB1>(sm);                // quad_perm xor1
                sm = dppadd<0x4E>(sm);                // quad_perm xor2
                sm = dppadd<0x124>(sm);               // row_ror:4
                sm = dppadd<0x128>(sm);               // row_ror:8
                sm += __int_as_float(__builtin_amdgcn_ds_swizzle(
                          __float_as_int(sm), 0x401F));   // xor16 within 32
                c = __fdividef(ex, sm);
            }
            H8 pk;
            pk.a = __floats2half2_rn(c * uh[0], c * uh[1]);
            pk.b = __floats2half2_rn(c * uh[2], c * uh[3]);
            pk.c = __floats2half2_rn(c * uh[4], c * uh[5]);
            pk.d = __floats2half2_rn(c * uh[6], c * uh[7]);
            *(H8*)&redh[g & 1][w * 2 + bq][o * 16 + kk * 8] = pk;   // 1 b128
        }
    }
    __syncthreads();
    if (t < 256) {   // ---- epilogue fold(g=7) from redh[1] ------------------
        const int bqf = t >> 7;
        const int hx  = (t & 127) * 4;
        const __half* rp = &redh[1][0][0];
        float a0 = 0.f, a1 = 0.f, a2 = 0.f, a3 = 0.f;
        #pragma unroll
        for (int s = 0; s < 8; ++s) {
            H4 v = *(const H4*)(rp + (s * 2 + bqf) * 512 + hx);
            float2 f0 = __half22float2(v.a), f1 = __half22float2(v.b);
            a0 += f0.x; a1 += f0.y; a2 += f1.x; a3 += f1.y;
        }
        const int b = qh * 16 + 14 + bqf;
        H4 o4;
        o4.a = __floats2half2_rn(a0, a1);
        o4.b = __floats2half2_rn(a2, a3);
        *(H4*)(part + ((size_t)b * 256 + ch) * 512 + hx) = o4;
    }
}

// ---------------------------------------------------------------------------
// Reduce (round-4 proven): grid 512 = (b = bx>>3) x (q = bx&7: 64-e slice =
// 4 complete o's). 1024 threads: f = t&7 (16B = 8 halves), c0 = t>>3 (chunk
// row in [0,128)); 2 x 16B loads/thread, f32 accumulate, 3-stage LDS fold,
// squash tail. PHASE 0: vsum=v; 1: vsum+=v; 2: out[b][o][k]=v.
// ---------------------------------------------------------------------------
template<int PHASE>
__global__ __launch_bounds__(1024)
void reduce_kernel(const __half* __restrict__ part,
                   float* __restrict__ vsum,
                   float* __restrict__ out)
{
    __shared__ __align__(16) float sA[128][64];   // 32 KB
    __shared__ __align__(16) float sB[16][64];    //  4 KB
    const int bx = blockIdx.x;
    const int b  = bx >> 3;
    const int q  = bx & 7;
    const int t  = threadIdx.x;
    const int f  = t & 7;
    const int c0 = t >> 3;                        // chunk row in [0,128)

    const __half* p0 = part + ((size_t)b * 256 + c0) * 512 + q * 64 + f * 8;
    float acc[8] = {0.f, 0.f, 0.f, 0.f, 0.f, 0.f, 0.f, 0.f};
    #pragma unroll
    for (int rr = 0; rr < 2; ++rr) {              // rows c0, c0+128
        H8 v = *(const H8*)(p0 + (size_t)rr * 128 * 512);
        float2 f0 = __half22float2(v.a), f1 = __half22float2(v.b),
               f2 = __half22float2(v.c), f3 = __half22float2(v.d);
        acc[0] += f0.x; acc[1] += f0.y; acc[2] += f1.x; acc[3] += f1.y;
        acc[4] += f2.x; acc[5] += f2.y; acc[6] += f3.x; acc[7] += f3.y;
    }
    *(float4*)&sA[c0][f * 8]     = make_float4(acc[0], acc[1], acc[2], acc[3]);
    *(float4*)&sA[c0][f * 8 + 4] = make_float4(acc[4], acc[5], acc[6], acc[7]);
    __syncthreads();

    {                                             // 128 rows -> 16
        const int e = t & 63, r4 = t >> 6;        // r4 in [0,16)
        float sb = 0.f;
        #pragma unroll
        for (int k2 = 0; k2 < 8; ++k2) sb += sA[r4 + k2 * 16][e];
        sB[r4][e] = sb;
    }
    __syncthreads();

    if (t < 64) {                                 // one wave: 16 rows, squash
        float s1 = 0.f;
        #pragma unroll
        for (int r = 0; r < 16; ++r) s1 += sB[r][t];
        float sq = s1 * s1;
        #pragma unroll
        for (int off = 8; off >= 1; off >>= 1)
            sq += __shfl_xor(sq, off, 16);        // sum over 16 k within o
        float v = (sq / (1.f + sq) * rsqrtf(sq + 1e-7f)) * s1;
        const size_t idx = (size_t)b * 512 + q * 64 + t;
        if (PHASE == 2)      out[idx]   = v;      // e = o*16+k == [b][o][k]
        else if (PHASE == 1) vsum[idx] += v;
        else                 vsum[idx]  = v;
    }
}

// ---------------------------------------------------------------------------
extern "C" void kernel_launch(void* const* d_in, const int* in_sizes, int n_in,
                              void* d_out, int out_size, void* d_ws, size_t ws_size,
                              hipStream_t stream)
{
    const float* x = (const float*)d_in[0];
    const float* W = (const float*)d_in[1];
    float* out = (float*)d_out;
    char* ws = (char*)d_ws;

    const size_t partB = (size_t)64 * 256 * 512 * 2;   // 16 MB (fp16)
    const size_t vsumB = (size_t)64 * 512 * 4;         // 128 KB
    if (ws_size < partB + vsumB) return;               // never taken

    __half* part = (__half*)ws;
    float*  vsum = (float*)(ws + partB);

    // round 0: c uniform -> v0; vsum = v0
    pass_kernel<1><<<1024, 512, 0, stream>>>(x, W, vsum, part);
    reduce_kernel<0><<<512, 1024, 0, stream>>>(part, vsum, out);
    // round 1: logits = u_hat . v0 -> v1; vsum = v0 + v1
    pass_kernel<0><<<1024, 512, 0, stream>>>(x, W, vsum, part);
    reduce_kernel<1><<<512, 1024, 0, stream>>>(part, vsum, out);
    // round 2: logits = u_hat . (v0+v1) -> v2 = output
    pass_kernel<0><<<1024, 512, 0, stream>>>(x, W, vsum, part);
    reduce_kernel<2><<<512, 1024, 0, stream>>>(part, vsum, out);
}